// Round 1
// baseline (33.201 us; speedup 1.0000x reference)
//
#include <hip/hip_runtime.h>
#include <math.h>

// Morph2d: weighted 3x3 window min/max lerp.
// out = min_tap + (max_tap - min_tap) * sigmoid(10*percentile[c]) - 10*bias[c]
// tap(i,j) = (x_padded[y+i-1][x+j-1] + 10*bias[c]) * kernel[c,i,j], pad raw = 0.

#define B_ 16
#define C_ 64
#define H_ 112
#define W_ 112

__global__ __launch_bounds__(256) void morph2d_kernel(
    const float* __restrict__ x,
    const float* __restrict__ kern,   // (1,C,3,3) -> C*9 floats
    const float* __restrict__ bias,   // (C,)
    const float* __restrict__ perc,   // (C,)
    float* __restrict__ out)
{
    const int groupsPerRow = W_ / 4;                       // 28
    const int totalGroups  = B_ * C_ * H_ * groupsPerRow;  // 3,211,264
    int g = blockIdx.x * blockDim.x + threadIdx.x;
    if (g >= totalGroups) return;

    int gx   = g % groupsPerRow;
    int rest = g / groupsPerRow;
    int y    = rest % H_;
    int bc   = rest / H_;          // b*C + c
    int c    = bc % C_;

    float biasv = bias[c] * 10.0f;
    float p = 1.0f / (1.0f + expf(-perc[c] * 10.0f));

    float k[9];
    #pragma unroll
    for (int i = 0; i < 9; ++i) k[i] = kern[c * 9 + i];

    const float* plane = x + (size_t)bc * (H_ * W_);
    int x0 = gx * 4;

    // raw[row][col]: 3 rows (y-1..y+1) x 6 cols (x0-1..x0+4), 0.0f in padding
    float raw[3][6];
    #pragma unroll
    for (int i = 0; i < 3; ++i) {
        #pragma unroll
        for (int j = 0; j < 6; ++j) raw[i][j] = 0.0f;
        int yy = y + i - 1;
        bool inY = ((unsigned)yy < (unsigned)H_);
        if (inY) {
            const float* rp = plane + yy * W_;
            float4 mid = *reinterpret_cast<const float4*>(rp + x0);  // aligned
            raw[i][1] = mid.x; raw[i][2] = mid.y; raw[i][3] = mid.z; raw[i][4] = mid.w;
            if (x0 > 0)      raw[i][0] = rp[x0 - 1];
            if (x0 + 4 < W_) raw[i][5] = rp[x0 + 4];
        }
    }

    float4 o;
    float* op = &o.x;
    #pragma unroll
    for (int q = 0; q < 4; ++q) {
        float vmax = -INFINITY, vmin = INFINITY;
        #pragma unroll
        for (int i = 0; i < 3; ++i) {
            #pragma unroll
            for (int j = 0; j < 3; ++j) {
                float t = (raw[i][q + j] + biasv) * k[i * 3 + j];
                vmax = fmaxf(vmax, t);
                vmin = fminf(vmin, t);
            }
        }
        op[q] = vmin + (vmax - vmin) * p - biasv;
    }

    float* orow = out + (size_t)bc * (H_ * W_) + (size_t)y * W_ + x0;
    *reinterpret_cast<float4*>(orow) = o;
}

extern "C" void kernel_launch(void* const* d_in, const int* in_sizes, int n_in,
                              void* d_out, int out_size, void* d_ws, size_t ws_size,
                              hipStream_t stream) {
    const float* x    = (const float*)d_in[0];
    const float* kern = (const float*)d_in[1];
    const float* bias = (const float*)d_in[2];
    const float* perc = (const float*)d_in[3];
    float* out = (float*)d_out;

    const int totalGroups = B_ * C_ * H_ * (W_ / 4);   // 3,211,264
    const int block = 256;
    const int grid  = (totalGroups + block - 1) / block;  // 12544
    morph2d_kernel<<<grid, block, 0, stream>>>(x, kern, bias, perc, out);
}

// Round 2
// 27.890 us; speedup vs baseline: 1.1904x; 1.1904x over previous
//
#include <hip/hip_runtime.h>
#include <math.h>

// Morph2d: weighted 3x3 window min/max lerp.
// tap(i,j) = (x_pad + 10*bias[c]) * k[c,i,j] = raw*k + bk  (bk = 10*bias*k, pad raw = 0)
// out = vmin + (vmax - vmin) * sigmoid(10*percentile[c]) - 10*bias[c]
//
// R2: 8x8 output tile per thread with y-sliding 3-row register window.
// VMEM per 64 outputs: 10 rows * (2 float4 + 2 scalar) loads + 8 * 2 float4 stores
// = 56 (0.875/output, was 2.5/output in R1).

#define B_ 16
#define C_ 64
#define H_ 112
#define W_ 112
#define TW 8
#define TH 8
#define GX (W_ / TW)   // 14
#define GY (H_ / TH)   // 14

__global__ __launch_bounds__(256) void morph2d_kernel(
    const float* __restrict__ x,
    const float* __restrict__ kern,   // (1,C,3,3)
    const float* __restrict__ bias,   // (C,)
    const float* __restrict__ perc,   // (C,)
    float* __restrict__ out)
{
    const int total = B_ * C_ * GY * GX;  // 200,704
    int t = blockIdx.x * blockDim.x + threadIdx.x;
    if (t >= total) return;

    int gx = t % GX;
    int r1 = t / GX;
    int ys = r1 % GY;
    int bc = r1 / GY;       // b*C + c
    int c  = bc % C_;

    float biasv = bias[c] * 10.0f;
    float p = 1.0f / (1.0f + expf(-perc[c] * 10.0f));

    float k[9], bk[9];
    #pragma unroll
    for (int i = 0; i < 9; ++i) {
        k[i]  = kern[c * 9 + i];
        bk[i] = k[i] * biasv;
    }

    const float* plane  = x   + (size_t)bc * (H_ * W_);
    float*       oplane = out + (size_t)bc * (H_ * W_);
    const int x0 = gx * TW;
    const int y0 = ys * TH;

    // 3-row sliding window of raw input (0.0f in padding), cols x0-1 .. x0+8
    float s[3][TW + 2];

#define LOADROW(slot, yy_) do {                                               \
        int _yy = (yy_);                                                      \
        if ((unsigned)_yy < (unsigned)H_) {                                   \
            const float* rp = plane + _yy * W_ + x0;                          \
            float4 a  = *reinterpret_cast<const float4*>(rp);                 \
            float4 b4 = *reinterpret_cast<const float4*>(rp + 4);             \
            s[slot][1] = a.x;  s[slot][2] = a.y;                              \
            s[slot][3] = a.z;  s[slot][4] = a.w;                              \
            s[slot][5] = b4.x; s[slot][6] = b4.y;                             \
            s[slot][7] = b4.z; s[slot][8] = b4.w;                             \
            s[slot][0] = (x0 > 0)       ? rp[-1] : 0.0f;                      \
            s[slot][9] = (x0 + TW < W_) ? rp[TW] : 0.0f;                      \
        } else {                                                              \
            _Pragma("unroll")                                                 \
            for (int _j = 0; _j < TW + 2; ++_j) s[slot][_j] = 0.0f;           \
        }                                                                     \
    } while (0)

    LOADROW(0, y0 - 1);
    LOADROW(1, y0);

    #pragma unroll
    for (int r = 0; r < TH; ++r) {
        const int st = r % 3;          // row y0+r-1  (kernel row 0)
        const int sm = (r + 1) % 3;    // row y0+r    (kernel row 1)
        const int sb = (r + 2) % 3;    // row y0+r+1  (kernel row 2)
        LOADROW(sb, y0 + r + 1);

        float o[TW];
        #pragma unroll
        for (int q = 0; q < TW; ++q) {
            float vmax = -INFINITY, vmin = INFINITY;
            #pragma unroll
            for (int j = 0; j < 3; ++j) {
                float t0 = fmaf(s[st][q + j], k[j],     bk[j]);
                float t1 = fmaf(s[sm][q + j], k[3 + j], bk[3 + j]);
                float t2 = fmaf(s[sb][q + j], k[6 + j], bk[6 + j]);
                vmax = fmaxf(fmaxf(vmax, t0), fmaxf(t1, t2));
                vmin = fminf(fminf(vmin, t0), fminf(t1, t2));
            }
            o[q] = fmaf(vmax - vmin, p, vmin) - biasv;
        }

        float* orow = oplane + (y0 + r) * W_ + x0;
        *reinterpret_cast<float4*>(orow)     = make_float4(o[0], o[1], o[2], o[3]);
        *reinterpret_cast<float4*>(orow + 4) = make_float4(o[4], o[5], o[6], o[7]);
    }
#undef LOADROW
}

extern "C" void kernel_launch(void* const* d_in, const int* in_sizes, int n_in,
                              void* d_out, int out_size, void* d_ws, size_t ws_size,
                              hipStream_t stream) {
    const float* x    = (const float*)d_in[0];
    const float* kern = (const float*)d_in[1];
    const float* bias = (const float*)d_in[2];
    const float* perc = (const float*)d_in[3];
    float* out = (float*)d_out;

    const int total = B_ * C_ * GY * GX;              // 200,704
    const int block = 256;
    const int grid  = (total + block - 1) / block;    // 784
    morph2d_kernel<<<grid, block, 0, stream>>>(x, kern, bias, perc, out);
}

// Round 4
// 26.027 us; speedup vs baseline: 1.2756x; 1.0716x over previous
//
#include <hip/hip_runtime.h>
#include <math.h>

// Morph2d: weighted 3x3 window min/max lerp.
// tap(i,j) = (x_pad + 10*bias[c]) * k[c,i,j] = raw*k + bk  (bk = 10*bias*k, pad raw = 0)
// out = vmin + (vmax - vmin) * sigmoid(10*percentile[c]) - 10*bias[c]
//
// R4 = R3 with clang ext-vector type for nontemporal stores (HIP float4 is a
// class type the builtin rejects). 8x4 tile/thread, all 6 input rows preloaded
// (24 independent loads in flight), 401K threads = 24.5 waves/CU.

#define B_ 16
#define C_ 64
#define H_ 112
#define W_ 112
#define TW 8
#define TH 4
#define GX (W_ / TW)   // 14
#define GY (H_ / TH)   // 28

typedef float f32x4 __attribute__((ext_vector_type(4)));

__global__ __launch_bounds__(256) void morph2d_kernel(
    const float* __restrict__ x,
    const float* __restrict__ kern,   // (1,C,3,3)
    const float* __restrict__ bias,   // (C,)
    const float* __restrict__ perc,   // (C,)
    float* __restrict__ out)
{
    const int total = B_ * C_ * GY * GX;  // 401,408
    int t = blockIdx.x * blockDim.x + threadIdx.x;
    if (t >= total) return;

    int gx = t % GX;
    int r1 = t / GX;
    int ys = r1 % GY;
    int bc = r1 / GY;       // b*C + c
    int c  = bc % C_;

    float biasv = bias[c] * 10.0f;
    float p = 1.0f / (1.0f + expf(-perc[c] * 10.0f));

    const float* plane  = x   + (size_t)bc * (H_ * W_);
    float*       oplane = out + (size_t)bc * (H_ * W_);
    const int x0 = gx * TW;
    const int y0 = ys * TH;

    // Preload all TH+2 = 6 raw input rows (0.0f in padding), cols x0-1 .. x0+8.
    // All loads are independent -> issued back-to-back, one vmcnt wait.
    float s[TH + 2][TW + 2];
    #pragma unroll
    for (int i = 0; i < TH + 2; ++i) {
        int yy = y0 + i - 1;
        if ((unsigned)yy < (unsigned)H_) {
            const float* rp = plane + yy * W_ + x0;
            f32x4 a  = *reinterpret_cast<const f32x4*>(rp);
            f32x4 b4 = *reinterpret_cast<const f32x4*>(rp + 4);
            s[i][1] = a.x;  s[i][2] = a.y;  s[i][3] = a.z;  s[i][4] = a.w;
            s[i][5] = b4.x; s[i][6] = b4.y; s[i][7] = b4.z; s[i][8] = b4.w;
            s[i][0] = (x0 > 0)       ? rp[-1] : 0.0f;
            s[i][9] = (x0 + TW < W_) ? rp[TW] : 0.0f;
        } else {
            #pragma unroll
            for (int j = 0; j < TW + 2; ++j) s[i][j] = 0.0f;
        }
    }

    float k[9], bk[9];
    #pragma unroll
    for (int i = 0; i < 9; ++i) {
        k[i]  = kern[c * 9 + i];
        bk[i] = k[i] * biasv;
    }

    #pragma unroll
    for (int r = 0; r < TH; ++r) {
        float o[TW];
        #pragma unroll
        for (int q = 0; q < TW; ++q) {
            float t0 = fmaf(s[r][q],     k[0], bk[0]);
            float t1 = fmaf(s[r][q + 1], k[1], bk[1]);
            float t2 = fmaf(s[r][q + 2], k[2], bk[2]);
            float vmax = fmaxf(fmaxf(t0, t1), t2);
            float vmin = fminf(fminf(t0, t1), t2);
            t0 = fmaf(s[r + 1][q],     k[3], bk[3]);
            t1 = fmaf(s[r + 1][q + 1], k[4], bk[4]);
            t2 = fmaf(s[r + 1][q + 2], k[5], bk[5]);
            vmax = fmaxf(vmax, fmaxf(fmaxf(t0, t1), t2));
            vmin = fminf(vmin, fminf(fminf(t0, t1), t2));
            t0 = fmaf(s[r + 2][q],     k[6], bk[6]);
            t1 = fmaf(s[r + 2][q + 1], k[7], bk[7]);
            t2 = fmaf(s[r + 2][q + 2], k[8], bk[8]);
            vmax = fmaxf(vmax, fmaxf(fmaxf(t0, t1), t2));
            vmin = fminf(vmin, fminf(fminf(t0, t1), t2));
            o[q] = fmaf(vmax - vmin, p, vmin) - biasv;
        }

        float* orow = oplane + (y0 + r) * W_ + x0;
        f32x4 lo = { o[0], o[1], o[2], o[3] };
        f32x4 hi = { o[4], o[5], o[6], o[7] };
        __builtin_nontemporal_store(lo, reinterpret_cast<f32x4*>(orow));
        __builtin_nontemporal_store(hi, reinterpret_cast<f32x4*>(orow + 4));
    }
}

extern "C" void kernel_launch(void* const* d_in, const int* in_sizes, int n_in,
                              void* d_out, int out_size, void* d_ws, size_t ws_size,
                              hipStream_t stream) {
    const float* x    = (const float*)d_in[0];
    const float* kern = (const float*)d_in[1];
    const float* bias = (const float*)d_in[2];
    const float* perc = (const float*)d_in[3];
    float* out = (float*)d_out;

    const int total = B_ * C_ * GY * GX;              // 401,408
    const int block = 256;
    const int grid  = (total + block - 1) / block;    // 1568
    morph2d_kernel<<<grid, block, 0, stream>>>(x, kern, bias, perc, out);
}